// Round 2
// baseline (265.814 us; speedup 1.0000x reference)
//
#include <hip/hip_runtime.h>
#include <stdint.h>

#define N_NODES 50000
#define N_EDGES 1600000
#define N_FEAT 128
#define CAP 64            // payload slots per row; Poisson(28.8) mean, +6.5 sigma
#define OVF_CAP 65536     // overflow list capacity (expected usage: ~0)

#define CONV_BLOCKS 1600  // 1600*256 threads, 4 edges/thread = 1,638,400 >= N_EDGES

// ---------------- threefry2x32 (bit-exact, KAT-verified vs Random123) ----------

struct KeyPair { uint32_t a, b; };

__host__ __device__ constexpr inline uint32_t rotl32(uint32_t x, int r) {
  return (x << r) | (x >> (32 - r));
}

__host__ __device__ constexpr inline KeyPair threefry2x32(uint32_t k0, uint32_t k1,
                                                          uint32_t x0, uint32_t x1) {
  const uint32_t ks0 = k0, ks1 = k1, ks2 = k0 ^ k1 ^ 0x1BD11BDAu;
  x0 += ks0;
  x1 += ks1;
  const int rotA[4] = {13, 15, 26, 6};
  const int rotB[4] = {17, 29, 16, 24};
  const uint32_t ks[3] = {ks0, ks1, ks2};
  for (int i = 0; i < 5; ++i) {
    const int* rot = (i & 1) ? rotB : rotA;
    for (int j = 0; j < 4; ++j) {
      x0 += x1;
      x1 = rotl32(x1, rot[j]);
      x1 ^= x0;
    }
    x0 += ks[(i + 1) % 3];
    x1 += ks[(i + 2) % 3] + (uint32_t)(i + 1);
  }
  return {x0, x1};
}

// mask_key = fold_in(key(42), 7); compile-time.
constexpr KeyPair MASK_KEY = threefry2x32(0u, 42u, 0u, 7u);

// Partitionable (counter-mode) random_bits: element i -> threefry(key, (0, i)), bits = b1^b2.
__device__ inline bool edge_keep(uint32_t e) {
  KeyPair r = threefry2x32(MASK_KEY.a, MASK_KEY.b, 0u, e);
  uint32_t bits = r.a ^ r.b;
  float u = __uint_as_float((bits >> 9) | 0x3f800000u) - 1.0f;
  return u < 0.9f;
}

// fp32 bits -> bf16 with round-to-nearest-even
__device__ inline uint32_t f2bf(uint32_t b) {
  return (b + 0x7fffu + ((b >> 16) & 1u)) >> 16;
}

// =================== PRIMARY PATH ==============================================
// payload word (u32): (col << 16) | bf16bits(val); cursor[r] = true count.
//
// Single-pass binning: x->bf16 conversion + direct per-row placement via global
// atomics. cursor[r] atomicAdd hands out unique slots; the slot write uses
// atomicExch so it is a memory-side (device-scope) op -- no cross-XCD dirty-line
// merge hazard on payload lines shared by writers on different XCDs. No LDS, no
// barriers, no intermediate coarse buffer, no pad-zeroing (gather masks by exact
// count). Replaces the old convA+partB two-pass radix partition.
__global__ void __launch_bounds__(256) convbin_kernel(const float* __restrict__ x,
                                                      uint32_t* __restrict__ xb,
                                                      const float* __restrict__ adj_vals,
                                                      const int* __restrict__ row,
                                                      const int* __restrict__ col,
                                                      uint32_t* __restrict__ payload,
                                                      uint32_t* __restrict__ cursor,
                                                      uint32_t* __restrict__ ovf_count,
                                                      uint64_t* __restrict__ ovf) {
  const int t = blockIdx.x * 256 + threadIdx.x;
  const int T = CONV_BLOCKS * 256;

  // phase 0: x -> bf16 (grid-stride, independent of binning)
  for (int i = t; i < (N_NODES * N_FEAT) / 4; i += T) {
    float4 f = ((const float4*)x)[i];
    uint2 o;
    o.x = f2bf(__float_as_uint(f.x)) | (f2bf(__float_as_uint(f.y)) << 16);
    o.y = f2bf(__float_as_uint(f.z)) | (f2bf(__float_as_uint(f.w)) << 16);
    ((uint2*)xb)[i] = o;
  }

  // phase 1: bin 4 consecutive edges per thread (vectorized edge loads)
  const int e4 = t * 4;
  if (e4 >= N_EDGES) return;
  const int4 r4 = ((const int4*)row)[t];
  const int4 c4 = ((const int4*)col)[t];
  const float4 a4 = ((const float4*)adj_vals)[t];
  const int rr[4] = {r4.x, r4.y, r4.z, r4.w};
  const int cc[4] = {c4.x, c4.y, c4.z, c4.w};
  const float aa[4] = {a4.x, a4.y, a4.z, a4.w};
#pragma unroll
  for (int k = 0; k < 4; ++k) {
    const uint32_t e = (uint32_t)(e4 + k);
    if (!edge_keep(e)) continue;
    const uint32_t r = (uint32_t)rr[k];
    const uint32_t c = (uint32_t)cc[k];
    const float v = aa[k] / 0.9f;
    const uint32_t idx = atomicAdd(&cursor[r], 1u);
    if (idx < CAP) {
      const uint32_t w = (c << 16) | f2bf(__float_as_uint(v));
      atomicExch(&payload[(size_t)r * CAP + idx], w);
    } else {
      const uint32_t oi = atomicAdd(ovf_count, 1u);
      if (oi < OVF_CAP)
        ovf[oi] = ((uint64_t)r << 48) | ((uint64_t)c << 32) | (uint64_t)__float_as_uint(v);
    }
  }
}

// Gather from bf16 x: 16-lane teams per row (dwordx4 = 8 feats/lane), 16 teams
// per 256-thread block. Payload chunks preloaded (NT); invalid tail words are
// zero-masked in registers (uniform-per-team selects) -- contribution exactly 0.
// x loads are cached (L2 reuse is the point); payload loads / out stores are NT.
typedef float f4v __attribute__((ext_vector_type(4)));

__global__ void __launch_bounds__(256) gather_bf16_kernel(const uint32_t* __restrict__ xb,
                                                          const uint32_t* __restrict__ payload,
                                                          const uint32_t* __restrict__ cursor,
                                                          float* __restrict__ out) {
  int r = blockIdx.x * 16 + (threadIdx.x >> 4);
  int lane = threadIdx.x & 15;
  uint32_t base = (uint32_t)r * CAP;
  uint32_t cnt = cursor[r];
  if (cnt > CAP) cnt = CAP;                   // overflow rows clamped; rest via ovf_pack
  const uint4* x4 = (const uint4*)xb;         // row stride: 16 uint4 (128 bf16)

  float acc0 = 0.f, acc1 = 0.f, acc2 = 0.f, acc3 = 0.f;
  float acc4 = 0.f, acc5 = 0.f, acc6 = 0.f, acc7 = 0.f;

  // preload payload chunks this row needs (coalesced 64B per team, NT)
  uint32_t p0 = __builtin_nontemporal_load(payload + base + lane);
  uint32_t p1 = (cnt > 16u) ? __builtin_nontemporal_load(payload + base + 16 + lane) : 0u;
  uint32_t p2 = (cnt > 32u) ? __builtin_nontemporal_load(payload + base + 32 + lane) : 0u;
  uint32_t p3 = (cnt > 48u) ? __builtin_nontemporal_load(payload + base + 48 + lane) : 0u;

#define GSTEP(ww)                                                            \
  {                                                                          \
    uint32_t cc = (ww) >> 16;                                                \
    float vv = __uint_as_float((ww) << 16);                                  \
    uint4 a = x4[(size_t)cc * 16 + lane];                                    \
    acc0 += vv * __uint_as_float(a.x << 16);                                 \
    acc1 += vv * __uint_as_float(a.x & 0xffff0000u);                         \
    acc2 += vv * __uint_as_float(a.y << 16);                                 \
    acc3 += vv * __uint_as_float(a.y & 0xffff0000u);                         \
    acc4 += vv * __uint_as_float(a.z << 16);                                 \
    acc5 += vv * __uint_as_float(a.z & 0xffff0000u);                         \
    acc6 += vv * __uint_as_float(a.w << 16);                                 \
    acc7 += vv * __uint_as_float(a.w & 0xffff0000u);                         \
  }

  // lim is uniform across the 16-lane team (cnt uniform) -> selects/branches
  // stay team-uniform; masked words become ww=0 => vv=0, cc=0 (L1-hot row 0).
#define PCHUNK(preg, mm)                                                     \
  for (int j = 0; j < (mm); j += 8) {                                        \
    int lim = (mm) - j;                                                      \
    uint32_t w0 = __shfl((preg), j + 0, 16);                                 \
    uint32_t w1 = __shfl((preg), j + 1, 16);                                 \
    uint32_t w2 = __shfl((preg), j + 2, 16);                                 \
    uint32_t w3 = __shfl((preg), j + 3, 16);                                 \
    uint32_t w4 = __shfl((preg), j + 4, 16);                                 \
    uint32_t w5 = __shfl((preg), j + 5, 16);                                 \
    uint32_t w6 = __shfl((preg), j + 6, 16);                                 \
    uint32_t w7 = __shfl((preg), j + 7, 16);                                 \
    w1 = (1 < lim) ? w1 : 0u;                                                \
    w2 = (2 < lim) ? w2 : 0u;                                                \
    w3 = (3 < lim) ? w3 : 0u;                                                \
    w4 = (4 < lim) ? w4 : 0u;                                                \
    w5 = (5 < lim) ? w5 : 0u;                                                \
    w6 = (6 < lim) ? w6 : 0u;                                                \
    w7 = (7 < lim) ? w7 : 0u;                                                \
    GSTEP(w0) GSTEP(w1) GSTEP(w2) GSTEP(w3)                                  \
    GSTEP(w4) GSTEP(w5) GSTEP(w6) GSTEP(w7)                                  \
  }

  int rem = (int)cnt;
  if (rem > 0) {
    PCHUNK(p0, min(rem, 16));
    rem -= 16;
    if (rem > 0) {
      PCHUNK(p1, min(rem, 16));
      rem -= 16;
      if (rem > 0) {
        PCHUNK(p2, min(rem, 16));
        rem -= 16;
        if (rem > 0) {
          PCHUNK(p3, min(rem, 16));
        }
      }
    }
  }
#undef PCHUNK
#undef GSTEP

  // lane stores feats 8*lane .. 8*lane+7 -> 512B contiguous per team (NT)
  f4v lo, hi;
  lo.x = acc0; lo.y = acc1; lo.z = acc2; lo.w = acc3;
  hi.x = acc4; hi.y = acc5; hi.z = acc6; hi.w = acc7;
  f4v* o = (f4v*)out + (size_t)r * 32 + lane * 2;
  __builtin_nontemporal_store(lo, o);
  __builtin_nontemporal_store(hi, o + 1);
}

// exact cleanup for packed (row,col,f32val) overflow entries (expected: none)
__global__ void __launch_bounds__(256) ovf_pack_kernel(const float* __restrict__ x,
                                                       const uint32_t* __restrict__ ovf_count,
                                                       const uint64_t* __restrict__ ovf,
                                                       float* __restrict__ out) {
  uint32_t n = *ovf_count;
  if (n > OVF_CAP) n = OVF_CAP;
  int g = (int)((blockIdx.x * blockDim.x + threadIdx.x) >> 7);
  int f = threadIdx.x & 127;
  const int ngroups = (64 * 256) >> 7;
  for (uint32_t oi = g; oi < n; oi += ngroups) {
    uint64_t p = ovf[oi];
    uint32_t r = (uint32_t)(p >> 48);
    uint32_t c = (uint32_t)((p >> 32) & 0xFFFFu);
    float v = __uint_as_float((uint32_t)p);
    atomicAdd(&out[(size_t)r * N_FEAT + f], v * x[(size_t)c * N_FEAT + f]);
  }
}

// =================== FALLBACK: fused atomic scatter ============================

__global__ void __launch_bounds__(256) scatter_fused_kernel(const float* __restrict__ x,
                                                            const float* __restrict__ adj_vals,
                                                            const int* __restrict__ row,
                                                            const int* __restrict__ col,
                                                            float* __restrict__ out) {
  long long t = (long long)blockIdx.x * blockDim.x + threadIdx.x;
  int e = (int)(t >> 6);
  int lane = (int)(t & 63);
  if (e >= N_EDGES) return;
  if (!edge_keep((uint32_t)e)) return;
  float v = adj_vals[e] / 0.9f;
  float2 xf = *(const float2*)(x + (long long)col[e] * N_FEAT + lane * 2);
  float* dst = out + (long long)row[e] * N_FEAT + lane * 2;
  atomicAdd(dst, v * xf.x);
  atomicAdd(dst + 1, v * xf.y);
}

// ---------------- launch --------------------------------------------------------

extern "C" void kernel_launch(void* const* d_in, const int* in_sizes, int n_in,
                              void* d_out, int out_size, void* d_ws, size_t ws_size,
                              hipStream_t stream) {
  const float* x        = (const float*)d_in[0];
  const float* adj_vals = (const float*)d_in[1];
  const int*   row      = (const int*)d_in[2];
  const int*   col      = (const int*)d_in[3];
  float* out = (float*)d_out;

  // ---- workspace layout ----
  // cursor and ovf_count contiguous at offset 0 -> one memset clears both.
  size_t a_cursor  = 0;                                                   // N u32
  size_t a_ovfc    = (size_t)N_NODES * 4;                                 // 1 u32
  size_t a_ovf     = (a_ovfc + 4 + 255) & ~255ull;                        // OVF_CAP u64
  size_t a_payload = (a_ovf + (size_t)OVF_CAP * 8 + 255) & ~255ull;       // N*CAP u32
  size_t a_xb      = (a_payload + (size_t)N_NODES * CAP * 4 + 255) & ~255ull;  // N*F bf16
  size_t need      = a_xb + (size_t)N_NODES * N_FEAT * 2;

  if (ws_size >= need) {
    uint32_t* cursor    = (uint32_t*)((char*)d_ws + a_cursor);
    uint32_t* ovf_count = (uint32_t*)((char*)d_ws + a_ovfc);
    uint64_t* ovf       = (uint64_t*)((char*)d_ws + a_ovf);
    uint32_t* payload   = (uint32_t*)((char*)d_ws + a_payload);
    uint32_t* xb        = (uint32_t*)((char*)d_ws + a_xb);

    hipMemsetAsync(d_ws, 0, (size_t)N_NODES * 4 + 4, stream);  // cursor + ovf_count
    convbin_kernel<<<CONV_BLOCKS, 256, 0, stream>>>(x, xb, adj_vals, row, col,
                                                    payload, cursor, ovf_count, ovf);
    gather_bf16_kernel<<<N_NODES / 16, 256, 0, stream>>>(xb, payload, cursor, out);
    ovf_pack_kernel<<<64, 256, 0, stream>>>(x, ovf_count, ovf, out);
  } else {
    hipMemsetAsync(d_out, 0, (size_t)out_size * sizeof(float), stream);
    long long total_threads = (long long)N_EDGES * 64;
    scatter_fused_kernel<<<(int)((total_threads + 255) / 256), 256, 0, stream>>>(
        x, adj_vals, row, col, out);
  }
}

// Round 4
// 162.040 us; speedup vs baseline: 1.6404x; 1.6404x over previous
//
#include <hip/hip_runtime.h>
#include <stdint.h>

#define N_NODES 50000
#define N_EDGES 1600000
#define N_FEAT 128
#define CAP 64            // final slots per row; Poisson(28.8) mean, +6.5 sigma
#define OVF_CAP 65536     // overflow list capacity (expected usage: ~0)

// radix-partition parameters
#define RSHIFT 8          // 256 rows per coarse bucket
#define BROWS 256
#define NB 196            // ceil(50000 / 256)
#define NWG_A 250         // pass-A workgroups; 250*1600 chunks * 4 edges = 1.6M exact
#define A_THREADS 1024
#define CHUNKS_PW 1600    // 4-edge chunks per pass-A wg
#define CAPW 56           // slots per (bucket, wg) segment; mean 29.4, ~+4.9 sigma

// ---------------- threefry2x32 (bit-exact, KAT-verified vs Random123) ----------

struct KeyPair { uint32_t a, b; };

__host__ __device__ constexpr inline uint32_t rotl32(uint32_t x, int r) {
  return (x << r) | (x >> (32 - r));
}

__host__ __device__ constexpr inline KeyPair threefry2x32(uint32_t k0, uint32_t k1,
                                                          uint32_t x0, uint32_t x1) {
  const uint32_t ks0 = k0, ks1 = k1, ks2 = k0 ^ k1 ^ 0x1BD11BDAu;
  x0 += ks0;
  x1 += ks1;
  const int rotA[4] = {13, 15, 26, 6};
  const int rotB[4] = {17, 29, 16, 24};
  const uint32_t ks[3] = {ks0, ks1, ks2};
  for (int i = 0; i < 5; ++i) {
    const int* rot = (i & 1) ? rotB : rotA;
    for (int j = 0; j < 4; ++j) {
      x0 += x1;
      x1 = rotl32(x1, rot[j]);
      x1 ^= x0;
    }
    x0 += ks[(i + 1) % 3];
    x1 += ks[(i + 2) % 3] + (uint32_t)(i + 1);
  }
  return {x0, x1};
}

// mask_key = fold_in(key(42), 7); compile-time.
constexpr KeyPair MASK_KEY = threefry2x32(0u, 42u, 0u, 7u);

// Partitionable (counter-mode) random_bits: element i -> threefry(key, (0, i)), bits = b1^b2.
__device__ inline bool edge_keep(uint32_t e) {
  KeyPair r = threefry2x32(MASK_KEY.a, MASK_KEY.b, 0u, e);
  uint32_t bits = r.a ^ r.b;
  float u = __uint_as_float((bits >> 9) | 0x3f800000u) - 1.0f;
  return u < 0.9f;
}

// fp32 bits -> bf16 with round-to-nearest-even
__device__ inline uint32_t f2bf(uint32_t b) {
  return (b + 0x7fffu + ((b >> 16) & 1u)) >> 16;
}

// true vector types (ext_vector_type) -- __builtin_nontemporal_* rejects HIP's
// class-type uint2/float4, but accepts these (identical layout & codegen).
typedef uint32_t u2v __attribute__((ext_vector_type(2)));
typedef float f4v __attribute__((ext_vector_type(4)));

// =================== PRIMARY PATH ==============================================
// coarse pack: (row << 48) | (col << 32) | f32bits(val)
// final payload (u32): (col << 16) | bf16bits(val); cursor[r] = exact count.

// Pass A (fused with x->bf16 conversion): per-wg compaction into (bucket, wg)
// segments using LDS counters only (no global atomics -- round-2 post-mortem:
// memory-side atomics cost ~100MB of HBM write traffic + serialize at HBM
// latency). Edge loads vectorized int4/float4 (4 edges/thread/iter); coarse and
// xb stores are non-temporal (consumed next kernel from HBM; keep L2 clean).
__global__ void __launch_bounds__(A_THREADS) convA_kernel(const float* __restrict__ x,
                                                          uint32_t* __restrict__ xb,
                                                          const float* __restrict__ adj_vals,
                                                          const int* __restrict__ row,
                                                          const int* __restrict__ col,
                                                          uint64_t* __restrict__ coarse,
                                                          uint32_t* __restrict__ lens,
                                                          uint32_t* __restrict__ ovf_count,
                                                          uint64_t* __restrict__ ovf) {
  __shared__ uint32_t cnt[NB];
  int wg = blockIdx.x;
  int tid = threadIdx.x;
  if (tid < NB) cnt[tid] = 0;

  // phase 0: x -> bf16 (grid-stride; independent of partition data)
  const int gthreads = NWG_A * A_THREADS;
  for (int i = wg * A_THREADS + tid; i < (N_NODES * N_FEAT) / 4; i += gthreads) {
    float4 f = ((const float4*)x)[i];
    u2v o;
    o.x = f2bf(__float_as_uint(f.x)) | (f2bf(__float_as_uint(f.y)) << 16);
    o.y = f2bf(__float_as_uint(f.z)) | (f2bf(__float_as_uint(f.w)) << 16);
    __builtin_nontemporal_store(o, (u2v*)xb + i);
  }
  __syncthreads();  // cnt init visible

  // phase 1: bin 4-edge chunks (vector loads), LDS-atomic slot ranks
  for (int ch = tid; ch < CHUNKS_PW; ch += A_THREADS) {
    const int g = wg * CHUNKS_PW + ch;     // global chunk; edges [4g, 4g+4)
    const int4 r4 = ((const int4*)row)[g];
    const int4 c4 = ((const int4*)col)[g];
    const float4 a4 = ((const float4*)adj_vals)[g];
    const int rr[4] = {r4.x, r4.y, r4.z, r4.w};
    const int cc[4] = {c4.x, c4.y, c4.z, c4.w};
    const float aa[4] = {a4.x, a4.y, a4.z, a4.w};
#pragma unroll
    for (int k = 0; k < 4; ++k) {
      const uint32_t e = (uint32_t)(4 * g + k);
      if (!edge_keep(e)) continue;
      const uint32_t r = (uint32_t)rr[k];
      const uint32_t c = (uint32_t)cc[k];
      const float v = aa[k] / 0.9f;
      const uint32_t b = r >> RSHIFT;
      const uint32_t li = atomicAdd(&cnt[b], 1u);
      const uint64_t p = ((uint64_t)r << 48) | ((uint64_t)c << 32) | (uint64_t)__float_as_uint(v);
      if (li < CAPW) {
        __builtin_nontemporal_store(p, coarse + ((size_t)b * NWG_A + wg) * CAPW + li);
      } else {
        const uint32_t oi = atomicAdd(ovf_count, 1u);
        if (oi < OVF_CAP) ovf[oi] = p;
      }
    }
  }
  __syncthreads();
  if (tid < NB) lens[(size_t)tid * NWG_A + wg] = min(cnt[tid], (uint32_t)CAPW);
}

// Pass B: one 1024-thread wg per 256-row bucket. One WAVE per segment: lanes
// 0..len-1 read the segment contiguously (coalesced 448B), LDS-atomic rank into
// per-row counters, direct payload placement. No scan (round-1's scan was dead
// code: slen == lens[b][seg]), no padding (gather masks by exact count).
// 2 barriers total vs round-1's 18.
__global__ void __launch_bounds__(1024) partB_kernel(const uint64_t* __restrict__ coarse,
                                                     const uint32_t* __restrict__ lens,
                                                     uint32_t* __restrict__ payload,
                                                     uint32_t* __restrict__ cursor,
                                                     uint32_t* __restrict__ ovf_count,
                                                     uint64_t* __restrict__ ovf) {
  int b = blockIdx.x;
  int tid = threadIdx.x;
  __shared__ uint32_t cnt[BROWS];  // per local-row fill count
  if (tid < BROWS) cnt[tid] = 0;
  __syncthreads();

  int wave = tid >> 6;   // 16 waves
  int lane = tid & 63;
  for (int seg = wave; seg < NWG_A; seg += 16) {
    uint32_t len = lens[(size_t)b * NWG_A + seg];   // wave-uniform
    if (lane < (int)len) {
      uint64_t p = coarse[((size_t)b * NWG_A + seg) * CAPW + lane];
      uint32_t r = (uint32_t)(p >> 48);
      uint32_t rl = r & (BROWS - 1);
      uint32_t idx = atomicAdd(&cnt[rl], 1u);
      if (idx < CAP) {
        uint32_t c = (uint32_t)(p >> 32) & 0xFFFFu;
        payload[(size_t)r * CAP + idx] = (c << 16) | f2bf((uint32_t)p);
      } else {
        uint32_t oi = atomicAdd(ovf_count, 1u);
        if (oi < OVF_CAP) ovf[oi] = p;
      }
    }
  }
  __syncthreads();
  if (tid < BROWS) {
    uint32_t r = ((uint32_t)b << RSHIFT) + (uint32_t)tid;
    if (r < N_NODES) cursor[r] = min(cnt[tid], (uint32_t)CAP);
  }
}

// Gather from bf16 x: 16-lane teams per row (dwordx4 = 8 feats/lane), 16 teams
// per 256-thread block. Payload chunks preloaded (NT); invalid tail words are
// zero-masked in registers (uniform-per-team selects) -- contribution exactly 0.
// x loads are cached (L2 reuse is the point); payload loads / out stores are NT.
__global__ void __launch_bounds__(256) gather_bf16_kernel(const uint32_t* __restrict__ xb,
                                                          const uint32_t* __restrict__ payload,
                                                          const uint32_t* __restrict__ cursor,
                                                          float* __restrict__ out) {
  int r = blockIdx.x * 16 + (threadIdx.x >> 4);
  int lane = threadIdx.x & 15;
  uint32_t base = (uint32_t)r * CAP;
  uint32_t cnt = cursor[r];
  if (cnt > CAP) cnt = CAP;                   // overflow rows clamped; rest via ovf_pack
  const uint4* x4 = (const uint4*)xb;         // row stride: 16 uint4 (128 bf16)

  float acc0 = 0.f, acc1 = 0.f, acc2 = 0.f, acc3 = 0.f;
  float acc4 = 0.f, acc5 = 0.f, acc6 = 0.f, acc7 = 0.f;

  // preload payload chunks this row needs (coalesced 64B per team, NT)
  uint32_t p0 = __builtin_nontemporal_load(payload + base + lane);
  uint32_t p1 = (cnt > 16u) ? __builtin_nontemporal_load(payload + base + 16 + lane) : 0u;
  uint32_t p2 = (cnt > 32u) ? __builtin_nontemporal_load(payload + base + 32 + lane) : 0u;
  uint32_t p3 = (cnt > 48u) ? __builtin_nontemporal_load(payload + base + 48 + lane) : 0u;

#define GSTEP(ww)                                                            \
  {                                                                          \
    uint32_t cc = (ww) >> 16;                                                \
    float vv = __uint_as_float((ww) << 16);                                  \
    uint4 a = x4[(size_t)cc * 16 + lane];                                    \
    acc0 += vv * __uint_as_float(a.x << 16);                                 \
    acc1 += vv * __uint_as_float(a.x & 0xffff0000u);                         \
    acc2 += vv * __uint_as_float(a.y << 16);                                 \
    acc3 += vv * __uint_as_float(a.y & 0xffff0000u);                         \
    acc4 += vv * __uint_as_float(a.z << 16);                                 \
    acc5 += vv * __uint_as_float(a.z & 0xffff0000u);                         \
    acc6 += vv * __uint_as_float(a.w << 16);                                 \
    acc7 += vv * __uint_as_float(a.w & 0xffff0000u);                         \
  }

  // lim is uniform across the 16-lane team (cnt uniform) -> selects/branches
  // stay team-uniform; masked words become ww=0 => vv=0, cc=0 (L1-hot row 0).
#define PCHUNK(preg, mm)                                                     \
  for (int j = 0; j < (mm); j += 8) {                                        \
    int lim = (mm) - j;                                                      \
    uint32_t w0 = __shfl((preg), j + 0, 16);                                 \
    uint32_t w1 = __shfl((preg), j + 1, 16);                                 \
    uint32_t w2 = __shfl((preg), j + 2, 16);                                 \
    uint32_t w3 = __shfl((preg), j + 3, 16);                                 \
    uint32_t w4 = __shfl((preg), j + 4, 16);                                 \
    uint32_t w5 = __shfl((preg), j + 5, 16);                                 \
    uint32_t w6 = __shfl((preg), j + 6, 16);                                 \
    uint32_t w7 = __shfl((preg), j + 7, 16);                                 \
    w1 = (1 < lim) ? w1 : 0u;                                                \
    w2 = (2 < lim) ? w2 : 0u;                                                \
    w3 = (3 < lim) ? w3 : 0u;                                                \
    w4 = (4 < lim) ? w4 : 0u;                                                \
    w5 = (5 < lim) ? w5 : 0u;                                                \
    w6 = (6 < lim) ? w6 : 0u;                                                \
    w7 = (7 < lim) ? w7 : 0u;                                                \
    GSTEP(w0) GSTEP(w1) GSTEP(w2) GSTEP(w3)                                  \
    GSTEP(w4) GSTEP(w5) GSTEP(w6) GSTEP(w7)                                  \
  }

  int rem = (int)cnt;
  if (rem > 0) {
    PCHUNK(p0, min(rem, 16));
    rem -= 16;
    if (rem > 0) {
      PCHUNK(p1, min(rem, 16));
      rem -= 16;
      if (rem > 0) {
        PCHUNK(p2, min(rem, 16));
        rem -= 16;
        if (rem > 0) {
          PCHUNK(p3, min(rem, 16));
        }
      }
    }
  }
#undef PCHUNK
#undef GSTEP

  // lane stores feats 8*lane .. 8*lane+7 -> 512B contiguous per team (NT)
  f4v lo, hi;
  lo.x = acc0; lo.y = acc1; lo.z = acc2; lo.w = acc3;
  hi.x = acc4; hi.y = acc5; hi.z = acc6; hi.w = acc7;
  f4v* o = (f4v*)out + (size_t)r * 32 + lane * 2;
  __builtin_nontemporal_store(lo, o);
  __builtin_nontemporal_store(hi, o + 1);
}

// exact cleanup for packed (row,col,f32val) overflow entries (expected: none)
__global__ void __launch_bounds__(256) ovf_pack_kernel(const float* __restrict__ x,
                                                       const uint32_t* __restrict__ ovf_count,
                                                       const uint64_t* __restrict__ ovf,
                                                       float* __restrict__ out) {
  uint32_t n = *ovf_count;
  if (n > OVF_CAP) n = OVF_CAP;
  int g = (int)((blockIdx.x * blockDim.x + threadIdx.x) >> 7);
  int f = threadIdx.x & 127;
  const int ngroups = (64 * 256) >> 7;
  for (uint32_t oi = g; oi < n; oi += ngroups) {
    uint64_t p = ovf[oi];
    uint32_t r = (uint32_t)(p >> 48);
    uint32_t c = (uint32_t)((p >> 32) & 0xFFFFu);
    float v = __uint_as_float((uint32_t)p);
    atomicAdd(&out[(size_t)r * N_FEAT + f], v * x[(size_t)c * N_FEAT + f]);
  }
}

// =================== FALLBACK: fused atomic scatter ============================

__global__ void __launch_bounds__(256) scatter_fused_kernel(const float* __restrict__ x,
                                                            const float* __restrict__ adj_vals,
                                                            const int* __restrict__ row,
                                                            const int* __restrict__ col,
                                                            float* __restrict__ out) {
  long long t = (long long)blockIdx.x * blockDim.x + threadIdx.x;
  int e = (int)(t >> 6);
  int lane = (int)(t & 63);
  if (e >= N_EDGES) return;
  if (!edge_keep((uint32_t)e)) return;
  float v = adj_vals[e] / 0.9f;
  float2 xf = *(const float2*)(x + (long long)col[e] * N_FEAT + lane * 2);
  float* dst = out + (long long)row[e] * N_FEAT + lane * 2;
  atomicAdd(dst, v * xf.x);
  atomicAdd(dst + 1, v * xf.y);
}

// ---------------- launch --------------------------------------------------------

extern "C" void kernel_launch(void* const* d_in, const int* in_sizes, int n_in,
                              void* d_out, int out_size, void* d_ws, size_t ws_size,
                              hipStream_t stream) {
  const float* x        = (const float*)d_in[0];
  const float* adj_vals = (const float*)d_in[1];
  const int*   row      = (const int*)d_in[2];
  const int*   col      = (const int*)d_in[3];
  float* out = (float*)d_out;

  // ---- workspace layout ----
  size_t a_ovfc    = 0;                                                   // 1 u32
  size_t a_cursor  = 256;                                                 // N u32
  size_t a_lens    = (a_cursor + (size_t)N_NODES * 4 + 255) & ~255ull;    // NB*NWG_A u32
  size_t a_ovf     = (a_lens + (size_t)NB * NWG_A * 4 + 255) & ~255ull;   // OVF_CAP u64
  size_t a_coarse  = (a_ovf + (size_t)OVF_CAP * 8 + 255) & ~255ull;       // NB*NWG_A*CAPW u64
  size_t a_payload = (a_coarse + (size_t)NB * NWG_A * CAPW * 8 + 255) & ~255ull;  // N*CAP u32
  size_t a_xb      = (a_payload + (size_t)N_NODES * CAP * 4 + 255) & ~255ull;     // N*F bf16
  size_t need      = a_xb + (size_t)N_NODES * N_FEAT * 2;

  if (ws_size >= need) {
    uint32_t* ovf_count = (uint32_t*)((char*)d_ws + a_ovfc);
    uint32_t* cursor    = (uint32_t*)((char*)d_ws + a_cursor);
    uint32_t* lens      = (uint32_t*)((char*)d_ws + a_lens);
    uint64_t* ovf       = (uint64_t*)((char*)d_ws + a_ovf);
    uint64_t* coarse    = (uint64_t*)((char*)d_ws + a_coarse);
    uint32_t* payload   = (uint32_t*)((char*)d_ws + a_payload);
    uint32_t* xb        = (uint32_t*)((char*)d_ws + a_xb);

    hipMemsetAsync(ovf_count, 0, 4, stream);
    convA_kernel<<<NWG_A, A_THREADS, 0, stream>>>(x, xb, adj_vals, row, col,
                                                  coarse, lens, ovf_count, ovf);
    partB_kernel<<<NB, 1024, 0, stream>>>(coarse, lens, payload, cursor, ovf_count, ovf);
    gather_bf16_kernel<<<N_NODES / 16, 256, 0, stream>>>(xb, payload, cursor, out);
    ovf_pack_kernel<<<64, 256, 0, stream>>>(x, ovf_count, ovf, out);
  } else {
    hipMemsetAsync(d_out, 0, (size_t)out_size * sizeof(float), stream);
    long long total_threads = (long long)N_EDGES * 64;
    scatter_fused_kernel<<<(int)((total_threads + 255) / 256), 256, 0, stream>>>(
        x, adj_vals, row, col, out);
  }
}